// Round 1
// baseline (258.124 us; speedup 1.0000x reference)
//
#include <hip/hip_runtime.h>

// Malvar-He-Cutler demosaic. x: (N,1,H,W) fp32 bayer mosaic -> out: (N,3,H,W) fp32.
// Memory-bound: 64 MB in + 192 MB out -> ~45 us floor at ~6.3 TB/s.
// R1-R5 (prev session): 128x32 tile, float4, nontemporal stores, global_load_lds DMA.
// R6 (this round): 2-phase double-buffered pipeline with COUNTED vmcnt (T3/T4 minimum
//   template). Each block walks NT=4 consecutive y-tiles; tile t+1's DMA stays in
//   flight across a raw s_barrier while tile t computes (never vmcnt(0) mid-loop —
//   __syncthreads' compiler-emitted vmcnt(0) drain was the exposed-latency stall).
//   vmcnt ledger (per-wave vm ops: stage c in {4,5}, stores 12/tile, in-order retire):
//     prologue  vmcnt(4)  : allows only newest stage(t1) ops outstanding -> stage(t0) done
//     steady    vmcnt(16) : newer-than-stage(t) = 12 stores + c(>=4) next loads -> stage(t) done
//     epilogue  vmcnt(12) : newer-than-stage(t3) = 12 stores -> stage(t3) done
//   Edge halo fixup moved to REGISTERS (3 moves in 2 lanes) -> no 2nd barrier, no
//   fixup loads perturbing the vmcnt ledger. Rolling 5-row window (w[5][8], statically
//   unrolled) cuts ~24 live VGPRs; __launch_bounds__(256,4) targets 4 blocks/CU
//   (= the LDS cap: 2 x 19,008 B = 38,016 B).

constexpr int H = 1024, W = 1024;
constexpr int TILE_W = 128, TILE_H = 32;
constexpr int NT = 4;                                // y-tiles walked per block
constexpr int LDS_W = TILE_W + 4;                    // 132 floats, rows 16B-aligned
constexpr int LDS_H = TILE_H + 4;                    // 36
constexpr int CHUNKS_PER_ROW = LDS_W / 4;            // 33
constexpr int N_CHUNKS = CHUNKS_PER_ROW * LDS_H;     // 1188 = 4*256 + 164

typedef float v4f __attribute__((ext_vector_type(4)));
typedef __attribute__((address_space(1))) const unsigned int gu32;
typedef __attribute__((address_space(3))) unsigned int lu32;

__global__ __launch_bounds__(256, 4) void demosaic_kernel(
    const float* __restrict__ xin_all, const int* __restrict__ bp,
    float* __restrict__ out)
{
    __shared__ float tile[2][LDS_H][LDS_W];          // 38,016 B double buffer

    const int tx = threadIdx.x;                      // 0..31 -> 4 px wide
    const int ty = threadIdx.y;                      // 0..7  -> 4 rows each
    const int tid = ty * 32 + tx;
    const int x0 = blockIdx.x * TILE_W;
    const int ybase = blockIdx.y * (TILE_H * NT);
    const int n  = blockIdx.z;

    // Bayer pattern -> parity flips (uniform scalar loads).
    const int p0 = bp[0], p1 = bp[1];
    const int fi = (p0 == 2) || (p0 == 1 && p1 == 2);
    const int fj = (p0 == 2) || (p0 == 1 && p1 == 0);

    const float* __restrict__ xin = xin_all + (size_t)n * H * W;
    const int gx0 = x0 - 2;

    // Per-thread staging slots (tile-invariant): chunk idx -> row r, clamped col.
    // LDS float offset is simply 4*idx (chunks are linear in the tile).
    int rr[5]  = {0, 0, 0, 0, 0};
    int gxo[5] = {0, 0, 0, 0, 0};
    #pragma unroll
    for (int j = 0; j < 5; ++j) {
        const int idx = tid + 256 * j;
        if (idx < N_CHUNKS) {
            const int r = idx / CHUNKS_PER_ROW;      // magic-mul
            const int k = idx - r * CHUNKS_PER_ROW;
            rr[j]  = r;
            gxo[j] = min(max(gx0 + 4 * k, 0), W - 4);
        }
    }

    // Stage one 132x36 tile into buf via 16B global->LDS DMA.
    // Per wave: waves 0-2 issue 5 DMA instrs, wave 3 issues 4 (the {4,5} in the ledger).
    auto STAGE = [&](int buf, int y0) {
        float* const base = &tile[buf][0][0];
        #pragma unroll
        for (int j = 0; j < 5; ++j) {
            const int idx = tid + 256 * j;
            if (idx < N_CHUNKS) {
                const int gy = min(max(y0 + rr[j] - 2, 0), H - 1);
                __builtin_amdgcn_global_load_lds(
                    (gu32*)(xin + (size_t)gy * W + gxo[j]),
                    (lu32*)(base + 4 * idx), 16, 0, 0);
            }
        }
    };

    // Register-only edge fixup: only lane tx==0 of left-edge blocks / tx==31 of
    // right-edge blocks ever reads the clamp-affected LDS columns, and the values
    // it needs are already inside its own 8-float row (verified against the old
    // LDS fixup: left wants [r0,r0,r0,r1,...]=have[0,0,0,1,...]; right wants
    // [...,r1022,r1023,r1023,r1023]=have[...,2,3,3,3]).
    const bool lfix = (x0 == 0) && (tx == 0);
    const bool rfix = (x0 == W - TILE_W) && (tx == 31);

    const int xs  = tx * 4;
    const int ry0 = ty * 4;

    auto LOAD_ROW = [&](float (&d)[8], const float* p) {
        const v4f a = *(const v4f*)p;
        const v4f b = *(const v4f*)(p + 4);
        d[0] = a.x; d[1] = a.y; d[2] = a.z; d[3] = a.w;
        d[4] = b.x; d[5] = b.y; d[6] = b.z; d[7] = b.w;
        if (lfix) { d[3] = d[1]; d[1] = d[0]; d[2] = d[0]; }
        if (rfix) { d[4] = d[6]; d[5] = d[7]; d[6] = d[7]; }
    };

    // Compute one 128x32 tile from buf; rolling 5-row window, fully unrolled so all
    // w[] indices are compile-time constants (no scratch).
    auto COMPUTE = [&](int buf, int y0) {
        float w[5][8];
        #pragma unroll
        for (int m = 0; m < 4; ++m) LOAD_ROW(w[m], &tile[buf][ry0 + m][xs]);

        #pragma unroll
        for (int dr = 0; dr < 4; ++dr) {
            LOAD_ROW(w[(dr + 4) % 5], &tile[buf][ry0 + dr + 4][xs]);
            // rows dr..dr+4 live in slots (dr+m)%5
            #define WR_(m) (w[(dr + (m)) % 5])
            const int qi = (dr & 1) ^ fi;            // row parity = dr&1 (y0,ry0 even)

            float r4[4], g4[4], b4[4];
            #pragma unroll
            for (int p = 0; p < 4; ++p) {
                const float c   = WR_(2)[p + 2];
                const float up  = WR_(1)[p + 2], dn  = WR_(3)[p + 2];
                const float lf  = WR_(2)[p + 1], rt  = WR_(2)[p + 3];
                const float up2 = WR_(0)[p + 2], dn2 = WR_(4)[p + 2];
                const float lf2 = WR_(2)[p + 0], rt2 = WR_(2)[p + 4];
                const float dg  = WR_(1)[p + 1] + WR_(1)[p + 3]
                                + WR_(3)[p + 1] + WR_(3)[p + 3];

                const float axH = lf2 + rt2;
                const float axV = up2 + dn2;
                const float ax  = axH + axV;
                const float crossHV = (up + dn) + (lf + rt);

                const float s0 = (8.0f  * c + 4.0f * crossHV   - 2.0f * ax) * 0.0625f;
                const float s1 = (12.0f * c + 4.0f * dg        - 3.0f * ax) * 0.0625f;
                const float s2 = (10.0f * c + 8.0f * (lf + rt) - 2.0f * (axH + dg) + axV) * 0.0625f;
                const float s3 = (10.0f * c + 8.0f * (up + dn) - 2.0f * (axV + dg) + axH) * 0.0625f;

                const int qj = (p & 1) ^ fj;
                const int qt = (qi << 1) | qj;
                r4[p] = (qt == 0) ? c  : (qt == 1) ? s2 : (qt == 2) ? s3 : s1;
                g4[p] = (qi == qj) ? s0 : c;
                b4[p] = (qt == 0) ? s1 : (qt == 1) ? s3 : (qt == 2) ? s2 : c;
            }
            #undef WR_

            const int y = y0 + ry0 + dr;
            const size_t colbase = (size_t)(x0 + xs);
            v4f* const oR = (v4f*)(out + ((size_t)(n * 3 + 0) * H + y) * W + colbase);
            v4f* const oG = (v4f*)(out + ((size_t)(n * 3 + 1) * H + y) * W + colbase);
            v4f* const oB = (v4f*)(out + ((size_t)(n * 3 + 2) * H + y) * W + colbase);
            v4f vR = { r4[0], r4[1], r4[2], r4[3] };
            v4f vG = { g4[0], g4[1], g4[2], g4[3] };
            v4f vB = { b4[0], b4[1], b4[2], b4[3] };
            __builtin_nontemporal_store(vR, oR);
            __builtin_nontemporal_store(vG, oG);
            __builtin_nontemporal_store(vB, oB);
        }
    };

    // ---- 2-phase pipeline over NT=4 tiles (raw barriers + counted vmcnt) ----
    STAGE(0, ybase + 0 * TILE_H);
    STAGE(1, ybase + 1 * TILE_H);
    asm volatile("s_waitcnt vmcnt(4)" ::: "memory");   // stage(t0) landed
    __builtin_amdgcn_s_barrier();
    COMPUTE(0, ybase + 0 * TILE_H);
    __builtin_amdgcn_s_barrier();                      // buf0 free for overwrite

    STAGE(0, ybase + 2 * TILE_H);
    asm volatile("s_waitcnt vmcnt(16)" ::: "memory");  // stage(t1) landed; t2 in flight
    __builtin_amdgcn_s_barrier();
    COMPUTE(1, ybase + 1 * TILE_H);
    __builtin_amdgcn_s_barrier();                      // buf1 free for overwrite

    STAGE(1, ybase + 3 * TILE_H);
    asm volatile("s_waitcnt vmcnt(16)" ::: "memory");  // stage(t2) landed; t3 in flight
    __builtin_amdgcn_s_barrier();
    COMPUTE(0, ybase + 2 * TILE_H);

    asm volatile("s_waitcnt vmcnt(12)" ::: "memory");  // stage(t3) landed
    __builtin_amdgcn_s_barrier();
    COMPUTE(1, ybase + 3 * TILE_H);
}

extern "C" void kernel_launch(void* const* d_in, const int* in_sizes, int n_in,
                              void* d_out, int out_size, void* d_ws, size_t ws_size,
                              hipStream_t stream) {
    const float* x  = (const float*)d_in[0];
    const int*   bp = (const int*)d_in[1];
    float* out = (float*)d_out;
    const int N = in_sizes[0] / (H * W);               // 16
    dim3 grid(W / TILE_W, H / (TILE_H * NT), N);       // (8, 8, 16) = 1024 blocks
    dim3 block(32, 8, 1);
    demosaic_kernel<<<grid, block, 0, stream>>>(x, bp, out);
}

// Round 2
// 253.759 us; speedup vs baseline: 1.0172x; 1.0172x over previous
//
#include <hip/hip_runtime.h>

// Malvar-He-Cutler demosaic. x: (N,1,H,W) fp32 bayer mosaic -> out: (N,3,H,W) fp32.
// Memory-bound: 64 MB in + 192 MB out -> ~45 us floor at ~6.3 TB/s.
// R1-R5 (prev session): LDS-staged 128x32 tile, global_load_lds DMA, nontemporal
//   stores -> ~121 us kernel (2.3 TB/s, 36% of achievable).
// R6: 2-phase counted-vmcnt pipeline REGRESSED (~133 us): hipcc inserts its own
//   vmcnt(0) before ds_reads that depend on global_load_lds, so the counted wait
//   never applied and the drain also covered next-tile in-flight loads.
// R7 (this round): drop LDS entirely. Reuse here is tiny (5x vertical, 2x horiz)
//   and L1/L2 serve it (~400 MB amplified reads = ~11 us of L2 BW). No barriers,
//   no vmcnt drains, no DMA queue: pure load->compute->store stream, 16 waves/CU
//   hiding latency independently (the fill kernel's regime, 6.4 TB/s measured).
//   - block (64,4): wave = one full 256-px row -> 1 KB contiguous per store inst.
//   - per thread: 4-px strip, RPT=16 rows, rolling 5-row register window w[5][8]
//     (statically unrolled, all indices compile-time -> no scratch).
//   - 3 aligned v4f loads per new row (L/M/R cover the +/-2 halo; L,R hit the
//     lines fetched by neighbor lanes' M -> L1).
//   - 1-row software prefetch: row dr+3 issued before computing row dr.
//   - edge clamp = per-lane cndmask register fixes (no divergent loads).

constexpr int H = 1024, W = 1024;
constexpr int TILE_W = 256, TILE_H = 64;
constexpr int RPT = 16;                        // rows per thread

typedef float v4f __attribute__((ext_vector_type(4)));

__global__ __launch_bounds__(256, 4) void demosaic_kernel(
    const float* __restrict__ xin_all, const int* __restrict__ bp,
    float* __restrict__ out)
{
    const int tx = threadIdx.x;                // 0..63 -> 4 px wide
    const int ty = threadIdx.y;                // 0..3  -> 16 rows each
    const int x0 = blockIdx.x * TILE_W;
    const int n  = blockIdx.z;
    const int gx = x0 + tx * 4;                // output cols gx..gx+3
    const int ry0 = blockIdx.y * TILE_H + ty * RPT;

    // Bayer pattern -> parity flips (uniform scalar loads).
    const int p0 = bp[0], p1 = bp[1];
    const int fi = (p0 == 2) || (p0 == 1 && p1 == 2);
    const int fj = (p0 == 2) || (p0 == 1 && p1 == 0);

    const float* __restrict__ xin = xin_all + (size_t)n * H * W;

    // Horizontal halo: window cols gx-2..gx+5 from aligned v4f loads
    //   L=[gx-4,gx), M=[gx,gx+4), R=[gx+4,gx+8). Image-edge lanes clamp the
    //   load address (stay in-bounds) and fix the 2 halo values in registers.
    const bool lfix = (gx == 0);
    const bool rfix = (gx == W - 4);
    const int xl = lfix ? 0  : gx - 4;
    const int xr = rfix ? gx : gx + 4;

    float w[5][8];                             // rolling rows, slot of row r = (r+2)%5

    auto LOADROW = [&](int gy, v4f& L, v4f& M, v4f& R) {
        gy = min(max(gy, 0), H - 1);           // vertical replicate-pad
        const float* row = xin + (size_t)gy * W;
        L = *(const v4f*)(row + xl);
        M = *(const v4f*)(row + gx);
        R = *(const v4f*)(row + xr);
    };
    auto INSERT = [&](float (&d)[8], v4f L, v4f M, v4f R) {
        d[0] = lfix ? M.x : L.z;               // col gx-2 (edge: x[0])
        d[1] = lfix ? M.x : L.w;               // col gx-1
        d[2] = M.x; d[3] = M.y; d[4] = M.z; d[5] = M.w;
        d[6] = rfix ? M.w : R.x;               // col gx+4 (edge: x[W-1])
        d[7] = rfix ? M.w : R.y;               // col gx+5
    };

    // Prologue: rows ry0-2 .. ry0+2 into slots 0..4.
    {
        v4f L[5], M[5], R[5];
        #pragma unroll
        for (int m = 0; m < 5; ++m) LOADROW(ry0 - 2 + m, L[m], M[m], R[m]);
        #pragma unroll
        for (int m = 0; m < 5; ++m) INSERT(w[m], L[m], M[m], R[m]);
    }

    #pragma unroll
    for (int dr = 0; dr < RPT; ++dr) {
        // Prefetch row dr+3 (needed next iter); latency hides under this
        // iter's compute. Goes into slot dr%5 (= (dr+3+2)%5), which holds
        // row dr-2 and frees after this iter's compute.
        v4f Lp, Mp, Rp;
        if (dr < RPT - 1) LOADROW(ry0 + dr + 3, Lp, Mp, Rp);

        // Window rows dr-2+m live in slot (dr+m)%5.
        #define WR_(m) (w[(dr + (m)) % 5])
        const int qi = (dr & 1) ^ fi;          // ry0 even -> row parity = dr&1

        float r4[4], g4[4], b4[4];
        #pragma unroll
        for (int p = 0; p < 4; ++p) {
            const float c   = WR_(2)[p + 2];
            const float up  = WR_(1)[p + 2], dn  = WR_(3)[p + 2];
            const float lf  = WR_(2)[p + 1], rt  = WR_(2)[p + 3];
            const float up2 = WR_(0)[p + 2], dn2 = WR_(4)[p + 2];
            const float lf2 = WR_(2)[p + 0], rt2 = WR_(2)[p + 4];
            const float dg  = WR_(1)[p + 1] + WR_(1)[p + 3]
                            + WR_(3)[p + 1] + WR_(3)[p + 3];

            const float axH = lf2 + rt2;
            const float axV = up2 + dn2;
            const float ax  = axH + axV;
            const float crossHV = (up + dn) + (lf + rt);

            const float s0 = (8.0f  * c + 4.0f * crossHV   - 2.0f * ax) * 0.0625f;
            const float s1 = (12.0f * c + 4.0f * dg        - 3.0f * ax) * 0.0625f;
            const float s2 = (10.0f * c + 8.0f * (lf + rt) - 2.0f * (axH + dg) + axV) * 0.0625f;
            const float s3 = (10.0f * c + 8.0f * (up + dn) - 2.0f * (axV + dg) + axH) * 0.0625f;

            const int qj = (p & 1) ^ fj;       // gx even -> col parity = p&1
            const int qt = (qi << 1) | qj;
            r4[p] = (qt == 0) ? c  : (qt == 1) ? s2 : (qt == 2) ? s3 : s1;
            g4[p] = (qi == qj) ? s0 : c;
            b4[p] = (qt == 0) ? s1 : (qt == 1) ? s3 : (qt == 2) ? s2 : c;
        }
        #undef WR_

        const int y = ry0 + dr;
        const size_t rowoff = (size_t)y * W + gx;
        v4f* const oR = (v4f*)(out + (size_t)(n * 3 + 0) * H * W + rowoff);
        v4f* const oG = (v4f*)(out + (size_t)(n * 3 + 1) * H * W + rowoff);
        v4f* const oB = (v4f*)(out + (size_t)(n * 3 + 2) * H * W + rowoff);
        v4f vR = { r4[0], r4[1], r4[2], r4[3] };
        v4f vG = { g4[0], g4[1], g4[2], g4[3] };
        v4f vB = { b4[0], b4[1], b4[2], b4[3] };
        __builtin_nontemporal_store(vR, oR);
        __builtin_nontemporal_store(vG, oG);
        __builtin_nontemporal_store(vB, oB);

        if (dr < RPT - 1) INSERT(w[dr % 5], Lp, Mp, Rp);   // becomes row dr+3
    }
}

extern "C" void kernel_launch(void* const* d_in, const int* in_sizes, int n_in,
                              void* d_out, int out_size, void* d_ws, size_t ws_size,
                              hipStream_t stream) {
    const float* x  = (const float*)d_in[0];
    const int*   bp = (const int*)d_in[1];
    float* out = (float*)d_out;
    const int N = in_sizes[0] / (H * W);               // 16
    dim3 grid(W / TILE_W, H / TILE_H, N);              // (4, 16, 16) = 1024 blocks
    dim3 block(64, 4, 1);                              // wave = one full tile row
    demosaic_kernel<<<grid, block, 0, stream>>>(x, bp, out);
}

// Round 3
// 247.300 us; speedup vs baseline: 1.0438x; 1.0261x over previous
//
#include <hip/hip_runtime.h>

// Malvar-He-Cutler demosaic. x: (N,1,H,W) fp32 bayer mosaic -> out: (N,3,H,W) fp32.
// Memory-bound: 64 MB in + 192 MB out -> ~45 us floor at ~6.3 TB/s.
// R5 (prev session): LDS-staged 128x32 tile + global_load_lds DMA -> ~121 us.
// R6: counted-vmcnt pipeline REGRESSED (~133 us): compiler vmcnt(0) before ds_reads.
// R7: no-LDS rolling 5-row window REGRESSED (~131 us).
// Post-mortem R6/R7: the bottleneck was never synchronization — it's MEMORY-LEVEL
//   PARALLELISM. All variants kept only ~3-6 independent loads in flight per wave
//   (rolling window = dependent chain; LDS version = 5 DMA chunks then full drain).
//   Required in-flight traffic at 10.2 B/cyc/CU x ~600 cyc latency = ~6 KB/CU
//   (~96-128 x 64B lines); we sat at/below the knee -> ~2.3 TB/s in every variant.
// R8 (this round): maximize INDEPENDENT loads per wave.
//   - Each thread owns a 4x4 output patch; issues ALL 16 input loads up front as
//     one dependency-free batch: 8 rows x 2 unaligned-16B loads covering cols
//     gx-2..gx+5 (gfx950 supports 4B-aligned dwordx4).
//   - Then merge into an 8x8 register window (static indices), compute, 12 stores.
//   - No LDS, no barriers, no prefetch chain. 16 outstanding loads/wave;
//     at >=3 waves/SIMD that's >=192 outstanding/CU — past the BW-latency knee.
//   - Halo reuse (2x horiz, 5/4 vert) served by L1/L2 (~35 TB/s, not a limit).
//   - Edge clamp: clamp load ADDRESS into bounds, fix values with per-lane selects.

constexpr int H = 1024, W = 1024;

typedef float v4f  __attribute__((ext_vector_type(4)));
typedef float v4fu __attribute__((ext_vector_type(4), aligned(4)));  // 4B-aligned load

__global__ __launch_bounds__(256) void demosaic_kernel(
    const float* __restrict__ xin_all, const int* __restrict__ bp,
    float* __restrict__ out)
{
    const int tx  = threadIdx.x;                 // 0..63 -> 4 px wide
    const int ty  = threadIdx.y;                 // 0..3  -> 4 rows each
    const int gx  = blockIdx.x * 256 + tx * 4;   // output cols gx..gx+3 (even)
    const int ry0 = blockIdx.y * 16  + ty * 4;   // output rows ry0..ry0+3 (even)
    const int n   = blockIdx.z;

    // Bayer pattern -> parity flips (uniform scalar loads).
    const int p0 = bp[0], p1 = bp[1];
    const int fi = (p0 == 2) || (p0 == 1 && p1 == 2);
    const int fj = (p0 == 2) || (p0 == 1 && p1 == 0);

    const float* __restrict__ xin = xin_all + (size_t)n * H * W;

    // Window cols gx-2..gx+5 from two 16B loads: A@gx-2, B@gx+2 (both 8B-aligned).
    // Image-edge lanes clamp the address in-bounds and fix values via selects.
    const bool lfix = (gx == 0);
    const bool rfix = (gx == W - 4);
    const int  xa = lfix ? gx : gx - 2;
    const int  xb = rfix ? gx : gx + 2;

    // ---- issue ALL 16 loads as one independent batch (the MLP) ----
    v4f A[8], B[8];
    #pragma unroll
    for (int r = 0; r < 8; ++r) {
        const int gy = min(max(ry0 - 2 + r, 0), H - 1);   // vertical replicate-pad
        const float* row = xin + (size_t)gy * W;
        A[r] = *(const v4fu*)(row + xa);
        B[r] = *(const v4fu*)(row + xb);
    }

    // ---- merge into 8x8 window (all indices static; few cndmasks for edges) ----
    float w[8][8];
    #pragma unroll
    for (int r = 0; r < 8; ++r) {
        // normal: A = cols gx-2..gx+1, B = cols gx+2..gx+5
        // lfix:   A loaded at gx   -> cols gx..gx+3   (cols -2,-1 clamp to col 0)
        // rfix:   B loaded at gx   -> cols gx-2..gx+3 (cols W,W+1 clamp to col W-1)
        w[r][0] = A[r].x;
        w[r][1] = lfix ? A[r].x : A[r].y;
        w[r][2] = lfix ? A[r].x : A[r].z;
        w[r][3] = lfix ? A[r].y : A[r].w;
        w[r][4] = rfix ? B[r].z : B[r].x;
        w[r][5] = rfix ? B[r].w : B[r].y;
        w[r][6] = rfix ? B[r].w : B[r].z;
        w[r][7] = B[r].w;
    }

    // ---- compute 4 rows x 4 px, store 12 x 16B nontemporal ----
    #pragma unroll
    for (int dr = 0; dr < 4; ++dr) {
        const int qi = (dr & 1) ^ fi;            // ry0 even -> row parity = dr&1

        float r4[4], g4[4], b4[4];
        #pragma unroll
        for (int p = 0; p < 4; ++p) {
            const float c   = w[dr + 2][p + 2];
            const float up  = w[dr + 1][p + 2], dn  = w[dr + 3][p + 2];
            const float lf  = w[dr + 2][p + 1], rt  = w[dr + 2][p + 3];
            const float up2 = w[dr + 0][p + 2], dn2 = w[dr + 4][p + 2];
            const float lf2 = w[dr + 2][p + 0], rt2 = w[dr + 2][p + 4];
            const float dg  = w[dr + 1][p + 1] + w[dr + 1][p + 3]
                            + w[dr + 3][p + 1] + w[dr + 3][p + 3];

            const float axH = lf2 + rt2;
            const float axV = up2 + dn2;
            const float ax  = axH + axV;
            const float crossHV = (up + dn) + (lf + rt);

            const float s0 = (8.0f  * c + 4.0f * crossHV   - 2.0f * ax) * 0.0625f;
            const float s1 = (12.0f * c + 4.0f * dg        - 3.0f * ax) * 0.0625f;
            const float s2 = (10.0f * c + 8.0f * (lf + rt) - 2.0f * (axH + dg) + axV) * 0.0625f;
            const float s3 = (10.0f * c + 8.0f * (up + dn) - 2.0f * (axV + dg) + axH) * 0.0625f;

            const int qj = (p & 1) ^ fj;         // gx even -> col parity = p&1
            const int qt = (qi << 1) | qj;
            r4[p] = (qt == 0) ? c  : (qt == 1) ? s2 : (qt == 2) ? s3 : s1;
            g4[p] = (qi == qj) ? s0 : c;
            b4[p] = (qt == 0) ? s1 : (qt == 1) ? s3 : (qt == 2) ? s2 : c;
        }

        const int y = ry0 + dr;
        const size_t rowoff = (size_t)y * W + gx;
        v4f* const oR = (v4f*)(out + (size_t)(n * 3 + 0) * H * W + rowoff);
        v4f* const oG = (v4f*)(out + (size_t)(n * 3 + 1) * H * W + rowoff);
        v4f* const oB = (v4f*)(out + (size_t)(n * 3 + 2) * H * W + rowoff);
        v4f vR = { r4[0], r4[1], r4[2], r4[3] };
        v4f vG = { g4[0], g4[1], g4[2], g4[3] };
        v4f vB = { b4[0], b4[1], b4[2], b4[3] };
        __builtin_nontemporal_store(vR, oR);
        __builtin_nontemporal_store(vG, oG);
        __builtin_nontemporal_store(vB, oB);
    }
}

extern "C" void kernel_launch(void* const* d_in, const int* in_sizes, int n_in,
                              void* d_out, int out_size, void* d_ws, size_t ws_size,
                              hipStream_t stream) {
    const float* x  = (const float*)d_in[0];
    const int*   bp = (const int*)d_in[1];
    float* out = (float*)d_out;
    const int N = in_sizes[0] / (H * W);         // 16
    dim3 grid(W / 256, H / 16, N);               // (4, 64, 16) = 4096 blocks
    dim3 block(64, 4, 1);                        // wave = 256-px-wide 4-row band
    demosaic_kernel<<<grid, block, 0, stream>>>(x, bp, out);
}